// Round 1
// baseline (1497.814 us; speedup 1.0000x reference)
//
#include <hip/hip_runtime.h>
#include <hip/hip_bf16.h>

// ---------------------------------------------------------------------------
// SGCN: 3 x [GEMM -> normalized SpMM (+self loop) -> bias+ReLU] -> mean pool
//       -> linear classifier.
// Strategy: build CSR (dst-sorted) with precomputed edge coefficients once
// per launch, reuse across the 3 conv layers. One wave per destination row
// in SpMM (lane = channel) -> coalesced 256B gathers from cache-resident hW.
// ---------------------------------------------------------------------------

#define WS_ALIGN(x) (((x) + 255) & ~(size_t)255)

// ---- degree count: deg[v] = (# edges with dst==v); self loop added later --
__global__ void count_deg_kernel(const int* __restrict__ dst, int E,
                                 int* __restrict__ count) {
    int i = blockIdx.x * blockDim.x + threadIdx.x;
    if (i < E) atomicAdd(&count[dst[i]], 1);
}

// ---- single-block exclusive scan over counts -> rowptr, cursor, dinv ------
__global__ __launch_bounds__(1024)
void scan_kernel(const int* __restrict__ count, int N,
                 int* __restrict__ rowptr, int* __restrict__ cursor,
                 float* __restrict__ dinv) {
    __shared__ int wsum[16];
    __shared__ int sbase;
    const int lane = threadIdx.x & 63;
    const int wid  = threadIdx.x >> 6;
    if (threadIdx.x == 0) sbase = 0;
    __syncthreads();
    const int nchunk = (N + 1023) >> 10;
    for (int c = 0; c < nchunk; ++c) {
        int i = (c << 10) + threadIdx.x;
        int v = (i < N) ? count[i] : 0;
        if (i < N) dinv[i] = 1.0f / sqrtf((float)(v + 1));  // +1 = self loop
        // wave-level inclusive scan
        int x = v;
        #pragma unroll
        for (int off = 1; off < 64; off <<= 1) {
            int t = __shfl_up(x, off);
            if (lane >= off) x += t;
        }
        if (lane == 63) wsum[wid] = x;
        __syncthreads();
        int woff = 0;
        for (int wp = 0; wp < wid; ++wp) woff += wsum[wp];
        int incl = x + woff;
        int excl = incl - v;
        int base = sbase;
        if (i < N) { rowptr[i] = base + excl; cursor[i] = base + excl; }
        __syncthreads();
        if (threadIdx.x == 1023) sbase = base + incl;
        __syncthreads();
    }
    if (threadIdx.x == 0) rowptr[N] = sbase;
}

// ---- scatter edges into CSR segments, precompute coefficients -------------
__global__ void fill_csr_kernel(const int* __restrict__ src,
                                const int* __restrict__ dst,
                                const float* __restrict__ ea, int E,
                                const float* __restrict__ dinv,
                                int* __restrict__ cursor,
                                int* __restrict__ csrc,
                                float* __restrict__ ccoef) {
    int i = blockIdx.x * blockDim.x + threadIdx.x;
    if (i < E) {
        int s = src[i], d = dst[i];
        int p = atomicAdd(&cursor[d], 1);
        csrc[p]  = s;
        ccoef[p] = dinv[s] * dinv[d] * expf(-ea[i]);
    }
}

// ---- dense GEMM: Y[N,64] = X[N,K] @ W[K,64]; lane = out channel -----------
template <int K>
__global__ __launch_bounds__(256)
void gemm_kernel(const float* __restrict__ X, const float* __restrict__ W,
                 float* __restrict__ Y, int N) {
    __shared__ float sW[K * 64];
    for (int i = threadIdx.x; i < K * 64; i += 256) sW[i] = W[i];
    __syncthreads();
    int node = blockIdx.x * 4 + (threadIdx.x >> 6);
    int ch   = threadIdx.x & 63;
    if (node >= N) return;
    const float* xr = X + (size_t)node * K;
    float acc = 0.f;
    #pragma unroll
    for (int k = 0; k < K; ++k) acc = fmaf(xr[k], sW[k * 64 + ch], acc);
    Y[(size_t)node * 64 + ch] = acc;
}

// ---- SpMM: out[v] = relu(sum_{e:dst=v} coef*hW[src] + hW[v]/deg[v] + b) ---
__global__ __launch_bounds__(256)
void spmm_kernel(const float* __restrict__ HW,
                 const int* __restrict__ rowptr,
                 const int* __restrict__ csrc,
                 const float* __restrict__ ccoef,
                 const float* __restrict__ dinv,
                 const float* __restrict__ bias,
                 float* __restrict__ OUT, int N) {
    int node = blockIdx.x * 4 + (threadIdx.x >> 6);
    int lane = threadIdx.x & 63;
    if (node >= N) return;
    int beg = rowptr[node], end = rowptr[node + 1];
    float di = dinv[node];
    float a0 = di * di * HW[(size_t)node * 64 + lane];   // self loop (exp(0)=1)
    float a1 = 0.f, a2 = 0.f, a3 = 0.f;
    int j = beg;
    for (; j + 4 <= end; j += 4) {
        int   s0 = csrc[j],     s1 = csrc[j + 1], s2 = csrc[j + 2], s3 = csrc[j + 3];
        float c0 = ccoef[j],    c1 = ccoef[j + 1], c2 = ccoef[j + 2], c3 = ccoef[j + 3];
        a0 = fmaf(c0, HW[(size_t)s0 * 64 + lane], a0);
        a1 = fmaf(c1, HW[(size_t)s1 * 64 + lane], a1);
        a2 = fmaf(c2, HW[(size_t)s2 * 64 + lane], a2);
        a3 = fmaf(c3, HW[(size_t)s3 * 64 + lane], a3);
    }
    for (; j < end; ++j)
        a0 = fmaf(ccoef[j], HW[(size_t)csrc[j] * 64 + lane], a0);
    float v = (a0 + a1) + (a2 + a3) + bias[lane];
    OUT[(size_t)node * 64 + lane] = fmaxf(v, 0.f);
}

// ---- per-graph mean pool; batch is sorted, one block per graph ------------
__global__ __launch_bounds__(256)
void pool_kernel(const float* __restrict__ H, const int* __restrict__ batch,
                 int N, float* __restrict__ pooled) {
    int b    = blockIdx.x;
    int lane = threadIdx.x & 63;
    int wid  = threadIdx.x >> 6;
    __shared__ int sbeg, send;
    if (threadIdx.x == 0) {
        int lo = 0, hi = N;
        while (lo < hi) { int m = (lo + hi) >> 1; if (batch[m] < b) lo = m + 1; else hi = m; }
        sbeg = lo;
        lo = 0; hi = N;
        while (lo < hi) { int m = (lo + hi) >> 1; if (batch[m] < b + 1) lo = m + 1; else hi = m; }
        send = lo;
    }
    __syncthreads();
    int beg = sbeg, end = send;
    float acc = 0.f;
    for (int v = beg + wid; v < end; v += 4)
        acc += H[(size_t)v * 64 + lane];
    __shared__ float sacc[4][64];
    sacc[wid][lane] = acc;
    __syncthreads();
    if (wid == 0) {
        float s = sacc[0][lane] + sacc[1][lane] + sacc[2][lane] + sacc[3][lane];
        float cnt = (float)(end - beg);
        pooled[b * 64 + lane] = s / fmaxf(cnt, 1.0f);
    }
}

// ---- classifier: out[B,C] = pooled[B,64] @ Wc[64,C] + bc ------------------
__global__ __launch_bounds__(256)
void final_kernel(const float* __restrict__ pooled, const float* __restrict__ Wc,
                  const float* __restrict__ bc, float* __restrict__ out, int C) {
    int b = blockIdx.x;
    __shared__ float sp[64];
    if (threadIdx.x < 64) sp[threadIdx.x] = pooled[b * 64 + threadIdx.x];
    __syncthreads();
    for (int c = threadIdx.x; c < C; c += blockDim.x) {
        float acc = bc[c];
        #pragma unroll
        for (int k = 0; k < 64; ++k) acc = fmaf(sp[k], Wc[k * C + c], acc);
        out[b * C + c] = acc;
    }
}

extern "C" void kernel_launch(void* const* d_in, const int* in_sizes, int n_in,
                              void* d_out, int out_size, void* d_ws, size_t ws_size,
                              hipStream_t stream) {
    const float* x     = (const float*)d_in[0];
    const int*   esrc  = (const int*)  d_in[1];
    const int*   edst  = (const int*)  d_in[2];
    const float* ea    = (const float*)d_in[3];
    const int*   batch = (const int*)  d_in[4];
    const float* W0 = (const float*)d_in[5];  const float* b0 = (const float*)d_in[6];
    const float* W1 = (const float*)d_in[7];  const float* b1 = (const float*)d_in[8];
    const float* W2 = (const float*)d_in[9];  const float* b2 = (const float*)d_in[10];
    const float* Wc = (const float*)d_in[11]; const float* bc = (const float*)d_in[12];

    const int N    = in_sizes[4];          // batch array has one entry per node
    const int E    = in_sizes[1];
    const int H    = in_sizes[6];          // 64
    const int F_IN = in_sizes[5] / H;      // 128
    const int C    = in_sizes[12];         // 196
    const int B    = out_size / C;         // 16
    (void)F_IN; (void)n_in; (void)ws_size;

    // ---- carve workspace ----
    char* w = (char*)d_ws;
    auto alloc = [&](size_t bytes) { void* p = (void*)w; w += WS_ALIGN(bytes); return p; };
    int*   d_count  = (int*)  alloc((size_t)N * 4);
    float* d_dinv   = (float*)alloc((size_t)N * 4);
    int*   d_rowptr = (int*)  alloc((size_t)(N + 1) * 4);
    int*   d_cursor = (int*)  alloc((size_t)N * 4);
    int*   d_csrc   = (int*)  alloc((size_t)E * 4);
    float* d_ccoef  = (float*)alloc((size_t)E * 4);
    float* d_hA     = (float*)alloc((size_t)N * 64 * 4);
    float* d_tmp    = (float*)alloc((size_t)N * 64 * 4);
    float* d_pool   = (float*)alloc((size_t)B * 64 * 4);

    // ---- build CSR with precomputed coefficients (shared by all layers) ----
    hipMemsetAsync(d_count, 0, (size_t)N * 4, stream);
    count_deg_kernel<<<(E + 255) / 256, 256, 0, stream>>>(edst, E, d_count);
    scan_kernel<<<1, 1024, 0, stream>>>(d_count, N, d_rowptr, d_cursor, d_dinv);
    fill_csr_kernel<<<(E + 255) / 256, 256, 0, stream>>>(esrc, edst, ea, E, d_dinv,
                                                         d_cursor, d_csrc, d_ccoef);

    const int nblk = (N + 3) / 4;
    // ---- layer 0 (K=128) ----
    gemm_kernel<128><<<nblk, 256, 0, stream>>>(x, W0, d_tmp, N);
    spmm_kernel<<<nblk, 256, 0, stream>>>(d_tmp, d_rowptr, d_csrc, d_ccoef, d_dinv,
                                          b0, d_hA, N);
    // ---- layer 1 (K=64) ----
    gemm_kernel<64><<<nblk, 256, 0, stream>>>(d_hA, W1, d_tmp, N);
    spmm_kernel<<<nblk, 256, 0, stream>>>(d_tmp, d_rowptr, d_csrc, d_ccoef, d_dinv,
                                          b1, d_hA, N);
    // ---- layer 2 (K=64) ----
    gemm_kernel<64><<<nblk, 256, 0, stream>>>(d_hA, W2, d_tmp, N);
    spmm_kernel<<<nblk, 256, 0, stream>>>(d_tmp, d_rowptr, d_csrc, d_ccoef, d_dinv,
                                          b2, d_hA, N);

    // ---- pool + classifier ----
    pool_kernel<<<B, 256, 0, stream>>>(d_hA, batch, N, d_pool);
    final_kernel<<<B, 256, 0, stream>>>(d_pool, Wc, bc, (float*)d_out, C);
}

// Round 2
// 1198.192 us; speedup vs baseline: 1.2501x; 1.2501x over previous
//
#include <hip/hip_runtime.h>
#include <hip/hip_bf16.h>

// ---------------------------------------------------------------------------
// SGCN: 3 x [GEMM -> normalized SpMM (+self loop) -> bias+ReLU] -> mean pool
//       -> linear classifier.
// CSR (dst-sorted, precomputed coefficients) built once, reused 3 layers.
// SpMM: one wave per destination row, lane = channel -> coalesced gathers.
// Pool: two-stage deterministic reduction (R1 fix: was 16-block latency-bound
// kernel at 390us / 0.7% occupancy; now ~780 blocks + fixed-order reduce).
// ---------------------------------------------------------------------------

#define WS_ALIGN(x) (((x) + 255) & ~(size_t)255)
#define POOL_CHUNK 128

// ---- degree count: deg[v] = (# edges with dst==v); self loop added later --
__global__ void count_deg_kernel(const int* __restrict__ dst, int E,
                                 int* __restrict__ count) {
    int i = blockIdx.x * blockDim.x + threadIdx.x;
    if (i < E) atomicAdd(&count[dst[i]], 1);
}

// ---- single-block exclusive scan over counts -> rowptr, cursor, dinv ------
__global__ __launch_bounds__(1024)
void scan_kernel(const int* __restrict__ count, int N,
                 int* __restrict__ rowptr, int* __restrict__ cursor,
                 float* __restrict__ dinv) {
    __shared__ int wsum[16];
    __shared__ int sbase;
    const int lane = threadIdx.x & 63;
    const int wid  = threadIdx.x >> 6;
    if (threadIdx.x == 0) sbase = 0;
    __syncthreads();
    const int nchunk = (N + 1023) >> 10;
    for (int c = 0; c < nchunk; ++c) {
        int i = (c << 10) + threadIdx.x;
        int v = (i < N) ? count[i] : 0;
        if (i < N) dinv[i] = 1.0f / sqrtf((float)(v + 1));  // +1 = self loop
        int x = v;
        #pragma unroll
        for (int off = 1; off < 64; off <<= 1) {
            int t = __shfl_up(x, off);
            if (lane >= off) x += t;
        }
        if (lane == 63) wsum[wid] = x;
        __syncthreads();
        int woff = 0;
        for (int wp = 0; wp < wid; ++wp) woff += wsum[wp];
        int incl = x + woff;
        int excl = incl - v;
        int base = sbase;
        if (i < N) { rowptr[i] = base + excl; cursor[i] = base + excl; }
        __syncthreads();
        if (threadIdx.x == 1023) sbase = base + incl;
        __syncthreads();
    }
    if (threadIdx.x == 0) rowptr[N] = sbase;
}

// ---- scatter edges into CSR segments, precompute coefficients -------------
__global__ void fill_csr_kernel(const int* __restrict__ src,
                                const int* __restrict__ dst,
                                const float* __restrict__ ea, int E,
                                const float* __restrict__ dinv,
                                int* __restrict__ cursor,
                                int* __restrict__ csrc,
                                float* __restrict__ ccoef) {
    int i = blockIdx.x * blockDim.x + threadIdx.x;
    if (i < E) {
        int s = src[i], d = dst[i];
        int p = atomicAdd(&cursor[d], 1);
        csrc[p]  = s;
        ccoef[p] = dinv[s] * dinv[d] * expf(-ea[i]);
    }
}

// ---- dense GEMM: Y[N,64] = X[N,K] @ W[K,64]; lane = out channel -----------
template <int K>
__global__ __launch_bounds__(256)
void gemm_kernel(const float* __restrict__ X, const float* __restrict__ W,
                 float* __restrict__ Y, int N) {
    __shared__ float sW[K * 64];
    for (int i = threadIdx.x; i < K * 64; i += 256) sW[i] = W[i];
    __syncthreads();
    int node = blockIdx.x * 4 + (threadIdx.x >> 6);
    int ch   = threadIdx.x & 63;
    if (node >= N) return;
    const float* xr = X + (size_t)node * K;
    float acc = 0.f;
    #pragma unroll
    for (int k = 0; k < K; ++k) acc = fmaf(xr[k], sW[k * 64 + ch], acc);
    Y[(size_t)node * 64 + ch] = acc;
}

// ---- SpMM: out[v] = relu(sum_{e:dst=v} coef*hW[src] + hW[v]/deg[v] + b) ---
__global__ __launch_bounds__(256)
void spmm_kernel(const float* __restrict__ HW,
                 const int* __restrict__ rowptr,
                 const int* __restrict__ csrc,
                 const float* __restrict__ ccoef,
                 const float* __restrict__ dinv,
                 const float* __restrict__ bias,
                 float* __restrict__ OUT, int N) {
    int node = blockIdx.x * 4 + (threadIdx.x >> 6);
    int lane = threadIdx.x & 63;
    if (node >= N) return;
    int beg = rowptr[node], end = rowptr[node + 1];
    float di = dinv[node];
    float a0 = di * di * HW[(size_t)node * 64 + lane];   // self loop (exp(0)=1)
    float a1 = 0.f, a2 = 0.f, a3 = 0.f;
    int j = beg;
    for (; j + 4 <= end; j += 4) {
        int   s0 = csrc[j],     s1 = csrc[j + 1], s2 = csrc[j + 2], s3 = csrc[j + 3];
        float c0 = ccoef[j],    c1 = ccoef[j + 1], c2 = ccoef[j + 2], c3 = ccoef[j + 3];
        a0 = fmaf(c0, HW[(size_t)s0 * 64 + lane], a0);
        a1 = fmaf(c1, HW[(size_t)s1 * 64 + lane], a1);
        a2 = fmaf(c2, HW[(size_t)s2 * 64 + lane], a2);
        a3 = fmaf(c3, HW[(size_t)s3 * 64 + lane], a3);
    }
    for (; j < end; ++j)
        a0 = fmaf(ccoef[j], HW[(size_t)csrc[j] * 64 + lane], a0);
    float v = (a0 + a1) + (a2 + a3) + bias[lane];
    OUT[(size_t)node * 64 + lane] = fmaxf(v, 0.f);
}

// ---- pool stage 1: per-chunk per-graph partial sums -----------------------
// partial[blk][g][lane]; batch sorted -> register accumulate, flush on change
__global__ __launch_bounds__(256)
void pool1_kernel(const float* __restrict__ H, const int* __restrict__ batch,
                  int N, int B, float* __restrict__ partial) {
    __shared__ float part[4][16][64];
    int lane = threadIdx.x & 63, wid = threadIdx.x >> 6;
    for (int g = 0; g < 16; ++g) part[wid][g][lane] = 0.f;
    int beg = blockIdx.x * POOL_CHUNK;
    int end = min(beg + POOL_CHUNK, N);
    float acc = 0.f; int cur = -1;
    for (int v = beg + wid; v < end; v += 4) {
        int g = batch[v];
        if (g != cur) {
            if (cur >= 0) part[wid][cur][lane] += acc;
            cur = g; acc = 0.f;
        }
        acc += H[(size_t)v * 64 + lane];
    }
    if (cur >= 0) part[wid][cur][lane] += acc;
    __syncthreads();
    float* outp = partial + (size_t)blockIdx.x * B * 64;
    for (int idx = threadIdx.x; idx < B * 64; idx += 256) {
        int g = idx >> 6, l = idx & 63;
        outp[idx] = part[0][g][l] + part[1][g][l] + part[2][g][l] + part[3][g][l];
    }
}

// ---- pool stage 2: fixed-order reduce over blocks, divide by count --------
__global__ __launch_bounds__(256)
void pool2_kernel(const float* __restrict__ partial, int nblk, int B,
                  const int* __restrict__ batch, int N,
                  float* __restrict__ pooled) {
    int g = blockIdx.x;
    int lane = threadIdx.x & 63, wid = threadIdx.x >> 6;
    float acc = 0.f;
    for (int b = wid; b < nblk; b += 4)
        acc += partial[(size_t)b * B * 64 + g * 64 + lane];
    __shared__ float sacc[4][64];
    sacc[wid][lane] = acc;
    __syncthreads();
    if (wid == 0) {
        int lo = 0, hi = N;
        while (lo < hi) { int m = (lo + hi) >> 1; if (batch[m] < g) lo = m + 1; else hi = m; }
        int s0 = lo;
        lo = 0; hi = N;
        while (lo < hi) { int m = (lo + hi) >> 1; if (batch[m] < g + 1) lo = m + 1; else hi = m; }
        float cnt = (float)(lo - s0);
        float s = sacc[0][lane] + sacc[1][lane] + sacc[2][lane] + sacc[3][lane];
        pooled[g * 64 + lane] = s / fmaxf(cnt, 1.0f);
    }
}

// ---- classifier: out[B,C] = pooled[B,64] @ Wc[64,C] + bc ------------------
__global__ __launch_bounds__(256)
void final_kernel(const float* __restrict__ pooled, const float* __restrict__ Wc,
                  const float* __restrict__ bc, float* __restrict__ out, int C) {
    int b = blockIdx.x;
    __shared__ float sp[64];
    if (threadIdx.x < 64) sp[threadIdx.x] = pooled[b * 64 + threadIdx.x];
    __syncthreads();
    for (int c = threadIdx.x; c < C; c += blockDim.x) {
        float acc = bc[c];
        #pragma unroll
        for (int k = 0; k < 64; ++k) acc = fmaf(sp[k], Wc[k * C + c], acc);
        out[b * C + c] = acc;
    }
}

extern "C" void kernel_launch(void* const* d_in, const int* in_sizes, int n_in,
                              void* d_out, int out_size, void* d_ws, size_t ws_size,
                              hipStream_t stream) {
    const float* x     = (const float*)d_in[0];
    const int*   esrc  = (const int*)  d_in[1];
    const int*   edst  = (const int*)  d_in[2];
    const float* ea    = (const float*)d_in[3];
    const int*   batch = (const int*)  d_in[4];
    const float* W0 = (const float*)d_in[5];  const float* b0 = (const float*)d_in[6];
    const float* W1 = (const float*)d_in[7];  const float* b1 = (const float*)d_in[8];
    const float* W2 = (const float*)d_in[9];  const float* b2 = (const float*)d_in[10];
    const float* Wc = (const float*)d_in[11]; const float* bc = (const float*)d_in[12];

    const int N    = in_sizes[4];
    const int E    = in_sizes[1];
    const int H    = in_sizes[6];          // 64
    const int C    = in_sizes[12];         // 196
    const int B    = out_size / C;         // 16
    (void)H; (void)n_in; (void)ws_size;

    const int nblk_pool = (N + POOL_CHUNK - 1) / POOL_CHUNK;

    // ---- carve workspace ----
    char* w = (char*)d_ws;
    auto alloc = [&](size_t bytes) { void* p = (void*)w; w += WS_ALIGN(bytes); return p; };
    int*   d_count   = (int*)  alloc((size_t)N * 4);
    float* d_dinv    = (float*)alloc((size_t)N * 4);
    int*   d_rowptr  = (int*)  alloc((size_t)(N + 1) * 4);
    int*   d_cursor  = (int*)  alloc((size_t)N * 4);
    int*   d_csrc    = (int*)  alloc((size_t)E * 4);
    float* d_ccoef   = (float*)alloc((size_t)E * 4);
    float* d_hA      = (float*)alloc((size_t)N * 64 * 4);
    float* d_tmp     = (float*)alloc((size_t)N * 64 * 4);
    float* d_partial = (float*)alloc((size_t)nblk_pool * B * 64 * 4);
    float* d_pool    = (float*)alloc((size_t)B * 64 * 4);

    // ---- build CSR with precomputed coefficients (shared by all layers) ----
    hipMemsetAsync(d_count, 0, (size_t)N * 4, stream);
    count_deg_kernel<<<(E + 255) / 256, 256, 0, stream>>>(edst, E, d_count);
    scan_kernel<<<1, 1024, 0, stream>>>(d_count, N, d_rowptr, d_cursor, d_dinv);
    fill_csr_kernel<<<(E + 255) / 256, 256, 0, stream>>>(esrc, edst, ea, E, d_dinv,
                                                         d_cursor, d_csrc, d_ccoef);

    const int nblk = (N + 3) / 4;
    // ---- layer 0 (K=128) ----
    gemm_kernel<128><<<nblk, 256, 0, stream>>>(x, W0, d_tmp, N);
    spmm_kernel<<<nblk, 256, 0, stream>>>(d_tmp, d_rowptr, d_csrc, d_ccoef, d_dinv,
                                          b0, d_hA, N);
    // ---- layer 1 (K=64) ----
    gemm_kernel<64><<<nblk, 256, 0, stream>>>(d_hA, W1, d_tmp, N);
    spmm_kernel<<<nblk, 256, 0, stream>>>(d_tmp, d_rowptr, d_csrc, d_ccoef, d_dinv,
                                          b1, d_hA, N);
    // ---- layer 2 (K=64) ----
    gemm_kernel<64><<<nblk, 256, 0, stream>>>(d_hA, W2, d_tmp, N);
    spmm_kernel<<<nblk, 256, 0, stream>>>(d_tmp, d_rowptr, d_csrc, d_ccoef, d_dinv,
                                          b2, d_hA, N);

    // ---- pool + classifier ----
    pool1_kernel<<<nblk_pool, 256, 0, stream>>>(d_hA, batch, N, B, d_partial);
    pool2_kernel<<<B, 256, 0, stream>>>(d_partial, nblk_pool, B, batch, N, d_pool);
    final_kernel<<<B, 256, 0, stream>>>(d_pool, Wc, bc, (float*)d_out, C);
}